// Round 24
// baseline (306.996 us; speedup 1.0000x reference)
//
#include <hip/hip_runtime.h>
#include <hip/hip_bf16.h>
#include <cmath>

#define B_SZ 4096
#define N_SZ 8192
#define D_SZ 256
#define EPS 1e-8f
// zn is stored as fp8 e4m3 scaled by 16 -> acc = 256*cos.
// exp(sim-2) with sim = 2*cos = acc/128:  exp2( acc*log2e/128 - 2*log2e )
#define EXPC 0.01127105500694503f      // log2(e)/128
#define EXPB -2.8853900817779268f      // -2*log2(e)

typedef __attribute__((ext_vector_type(4))) float f32x4;
typedef __attribute__((ext_vector_type(4))) int   i32x4;
typedef __attribute__((ext_vector_type(8))) int   i32x8;

__device__ __forceinline__ void dma16(const void* g, void* l) {
    __builtin_amdgcn_global_load_lds(
        (const __attribute__((address_space(1))) unsigned int*)g,
        (__attribute__((address_space(3))) unsigned int*)l, 16, 0, 0);
}

// fp8 k-segment-transposed panel layout (1 byte/elem):
//   byte(row,k) = (row>>6)*16384 + (k>>4)*1024 + (row&63)*16 + (k&15)

// ---- Kernel 1: norms + pos (fp32 exact) + fp8 ZN + zero the reduce ctrl. ----
__global__ __launch_bounds__(256) void prep_kernel(const float* __restrict__ zi,
                                                   const float* __restrict__ zj,
                                                   char* __restrict__ znb,
                                                   float* __restrict__ pos,
                                                   float* __restrict__ accf,
                                                   unsigned* __restrict__ counter) {
    if (blockIdx.x == 0 && threadIdx.x == 0) { *accf = 0.0f; *counter = 0u; }
    const int wave = threadIdx.x >> 6, lane = threadIdx.x & 63;
    const int i = blockIdx.x * 4 + wave;               // 0..B-1
    float4 a = reinterpret_cast<const float4*>(zi + (size_t)i * D_SZ)[lane];
    float4 b = reinterpret_cast<const float4*>(zj + (size_t)i * D_SZ)[lane];
    float ssa = a.x * a.x + a.y * a.y + a.z * a.z + a.w * a.w;
    float ssb = b.x * b.x + b.y * b.y + b.z * b.z + b.w * b.w;
    float dab = a.x * b.x + a.y * b.y + a.z * b.z + a.w * b.w;
    #pragma unroll
    for (int off = 32; off; off >>= 1) {
        ssa += __shfl_xor(ssa, off, 64);
        ssb += __shfl_xor(ssb, off, 64);
        dab += __shfl_xor(dab, off, 64);
    }
    const float invna = 1.0f / fmaxf(sqrtf(ssa), EPS);
    const float invnb = 1.0f / fmaxf(sqrtf(ssb), EPS);
    if (lane == 0) {
        float p = dab * invna * invnb * 2.0f;
        pos[i] = p;
        pos[i + B_SZ] = p;
    }
    const float sa = invna * 16.0f, sb = invnb * 16.0f;
    const int koff = (lane >> 2) * 1024 + (lane & 3) * 4;
    {
        int pk = __builtin_amdgcn_cvt_pk_fp8_f32(a.x * sa, a.y * sa, 0, false);
        pk     = __builtin_amdgcn_cvt_pk_fp8_f32(a.z * sa, a.w * sa, pk, true);
        *reinterpret_cast<int*>(znb + (size_t)(i >> 6) * 16384 + koff + (i & 63) * 16) = pk;
    }
    {
        const int r = i + B_SZ;
        int pk = __builtin_amdgcn_cvt_pk_fp8_f32(b.x * sb, b.y * sb, 0, false);
        pk     = __builtin_amdgcn_cvt_pk_fp8_f32(b.z * sb, b.w * sb, pk, true);
        *reinterpret_cast<int*>(znb + (size_t)(r >> 6) * 16384 + koff + (r & 63) * 16) = pk;
    }
}

// ---- Kernel 2: r18 FROZEN (known-good 31.7us config) ----
__global__ __launch_bounds__(256, 3) void simlse_kernel(const char* __restrict__ znb,
                                                        float* __restrict__ partial) {
    __shared__ __attribute__((aligned(16))) char blds[32768];
    __shared__ float cs[4][256];

    const int t = threadIdx.x;
    const int wave = t >> 6, lane = t & 63;

    int rt, chunk;
    {
        const int x = blockIdx.x & 7;
        int j = blockIdx.x >> 3;
        int p = x;
        if (j >= 33) { j -= 33; p = x + 8; }
        if (j <= p) { rt = j; chunk = p; }
        else        { rt = j - (p + 1); chunk = 31 - p; }
    }
    const bool offdiag = (rt != chunk);

    const int rl = lane & 15;
    const int kg = lane >> 4;
    const int i0 = rt * 256 + wave * 64;

    #define STAGE(H)                                                              \
        {                                                                         \
            const char* gp = znb + (size_t)chunk * 65536 + (H) * 32768 + t * 16;  \
            char* lp = blds + t * 16;                                             \
            _Pragma("unroll")                                                     \
            for (int c = 0; c < 8; ++c) dma16(gp + c * 4096, lp + c * 4096);      \
        }

    STAGE(0);

    const char* ap = znb + (size_t)(rt * 4 + wave) * 16384 + rl * 16;
    i32x8 afrag[4][2];
    #pragma unroll
    for (int g = 0; g < 4; ++g)
        #pragma unroll
        for (int kc = 0; kc < 2; ++kc) {
            i32x4 lo = *reinterpret_cast<const i32x4*>(
                ap + (kc * 8 + kg * 2) * 1024 + g * 256);
            i32x4 hi = *reinterpret_cast<const i32x4*>(
                ap + (kc * 8 + kg * 2 + 1) * 1024 + g * 256);
            afrag[g][kc] = __builtin_shufflevector(lo, hi, 0, 1, 2, 3, 4, 5, 6, 7);
        }

    float s_acc[4][4];
    #pragma unroll
    for (int g = 0; g < 4; ++g)
        #pragma unroll
        for (int r = 0; r < 4; ++r) s_acc[g][r] = 0.0f;

    const char* bp0 = blds + kg * 2048 + rl * 16;

    i32x8 bf0, bf1;
    f32x4 accA[4], accB[4];

    #define LOADB(FL)                                                             \
        {                                                                         \
            const char* bq = bp0 + ((FL) >> 2) * 16384 + ((FL) & 3) * 256;        \
            i32x4 l0 = *reinterpret_cast<const i32x4*>(bq);                       \
            i32x4 l1 = *reinterpret_cast<const i32x4*>(bq + 1024);                \
            i32x4 l2 = *reinterpret_cast<const i32x4*>(bq + 8192);                \
            i32x4 l3 = *reinterpret_cast<const i32x4*>(bq + 9216);                \
            bf0 = __builtin_shufflevector(l0, l1, 0, 1, 2, 3, 4, 5, 6, 7);        \
            bf1 = __builtin_shufflevector(l2, l3, 0, 1, 2, 3, 4, 5, 6, 7);        \
        }

    #define MFMA8(ACC)                                                            \
        {                                                                         \
            _Pragma("unroll")                                                     \
            for (int g = 0; g < 4; ++g) ACC[g] = (f32x4){0.f, 0.f, 0.f, 0.f};     \
            _Pragma("unroll")                                                     \
            for (int g = 0; g < 4; ++g)                                           \
                asm("v_mfma_f32_16x16x128_f8f6f4 %0, %1, %2, %0"                  \
                    : "+v"(ACC[g]) : "v"(afrag[g][0]), "v"(bf0));                 \
            _Pragma("unroll")                                                     \
            for (int g = 0; g < 4; ++g)                                           \
                asm("v_mfma_f32_16x16x128_f8f6f4 %0, %1, %2, %0"                  \
                    : "+v"(ACC[g]) : "v"(afrag[g][1]), "v"(bf1));                 \
        }

    #define EXPSUM(ACC, F)                                                        \
        {                                                                         \
            float cthr = 0.0f;                                                    \
            _Pragma("unroll")                                                     \
            for (int g = 0; g < 4; ++g)                                           \
                _Pragma("unroll")                                                 \
                for (int r = 0; r < 4; ++r) {                                     \
                    float e = __builtin_amdgcn_exp2f(fmaf(ACC[g][r], EXPC, EXPB)); \
                    s_acc[g][r] += e;                                             \
                    cthr += e;                                                    \
                }                                                                 \
            cthr += __shfl_xor(cthr, 16, 64);                                     \
            cthr += __shfl_xor(cthr, 32, 64);                                     \
            if (offdiag && lane < 16)                                             \
                cs[wave][(F) * 16 + rl] = cthr;                                   \
        }

    __syncthreads();

    LOADB(0); MFMA8(accA);
    #pragma unroll 1
    for (int fo = 0; fo < 3; ++fo) {
        const int f1 = 2 * fo + 1, f2 = 2 * fo + 2;
        LOADB(f1); MFMA8(accB);
        asm volatile("s_nop 7");
        EXPSUM(accA, f1 - 1);
        LOADB(f2); MFMA8(accA);
        asm volatile("s_nop 7");
        EXPSUM(accB, f2 - 1);
    }
    LOADB(7); MFMA8(accB);
    asm volatile("s_nop 7");
    EXPSUM(accA, 6);

    __syncthreads();
    STAGE(1);
    EXPSUM(accB, 7);
    __syncthreads();

    LOADB(0); MFMA8(accA);
    #pragma unroll 1
    for (int fo = 0; fo < 3; ++fo) {
        const int f1 = 2 * fo + 1, f2 = 2 * fo + 2;
        LOADB(f1); MFMA8(accB);
        asm volatile("s_nop 7");
        EXPSUM(accA, 8 + f1 - 1);
        LOADB(f2); MFMA8(accA);
        asm volatile("s_nop 7");
        EXPSUM(accB, 8 + f2 - 1);
    }
    LOADB(7); MFMA8(accB);
    asm volatile("s_nop 7");
    EXPSUM(accA, 14);
    asm volatile("s_nop 7");
    EXPSUM(accB, 15);

    #pragma unroll
    for (int g = 0; g < 4; ++g)
        #pragma unroll
        for (int r = 0; r < 4; ++r) {
            float v = s_acc[g][r];
            #pragma unroll
            for (int off = 1; off < 16; off <<= 1) v += __shfl_xor(v, off, 64);
            if (rl == 0)
                partial[chunk * N_SZ + i0 + g * 16 + kg * 4 + r] = v;
        }

    if (offdiag) {
        __syncthreads();
        float v = cs[0][t] + cs[1][t] + cs[2][t] + cs[3][t];
        partial[rt * N_SZ + chunk * 256 + t] = v;
    }
    #undef STAGE
    #undef LOADB
    #undef MFMA8
    #undef EXPSUM
}

// ---- PROBE kernels (results never read; timing-only, x8 reps) ----
// MODE 0: r18 body (anchor). MODE 1: split-acc no-pingpong (ILP test).
// MODE 2: MFMA-only independent rate test (measures raw f8f6f4 cyc/instr).
template <int MODE>
__global__ __launch_bounds__(256, 3) void probe_kernel(const char* __restrict__ znb,
                                                       float* __restrict__ pout) {
    __shared__ __attribute__((aligned(16))) char blds[32768];
    __shared__ float cs[4][256];

    const int t = threadIdx.x;
    const int wave = t >> 6, lane = t & 63;

    int rt, chunk;
    {
        const int x = blockIdx.x & 7;
        int j = blockIdx.x >> 3;
        int p = x;
        if (j >= 33) { j -= 33; p = x + 8; }
        if (j <= p) { rt = j; chunk = p; }
        else        { rt = j - (p + 1); chunk = 31 - p; }
    }
    const bool offdiag = (rt != chunk);

    const int rl = lane & 15;
    const int kg = lane >> 4;
    const int i0 = rt * 256 + wave * 64;

    #define PSTAGE(H)                                                             \
        {                                                                         \
            const char* gp = znb + (size_t)chunk * 65536 + (H) * 32768 + t * 16;  \
            char* lp = blds + t * 16;                                             \
            _Pragma("unroll")                                                     \
            for (int c = 0; c < 8; ++c) dma16(gp + c * 4096, lp + c * 4096);      \
        }

    const char* ap = znb + (size_t)(rt * 4 + wave) * 16384 + rl * 16;
    i32x8 afrag[4][2];
    #pragma unroll
    for (int g = 0; g < 4; ++g)
        #pragma unroll
        for (int kc = 0; kc < 2; ++kc) {
            i32x4 lo = *reinterpret_cast<const i32x4*>(
                ap + (kc * 8 + kg * 2) * 1024 + g * 256);
            i32x4 hi = *reinterpret_cast<const i32x4*>(
                ap + (kc * 8 + kg * 2 + 1) * 1024 + g * 256);
            afrag[g][kc] = __builtin_shufflevector(lo, hi, 0, 1, 2, 3, 4, 5, 6, 7);
        }

    float s_acc[4][4];
    #pragma unroll
    for (int g = 0; g < 4; ++g)
        #pragma unroll
        for (int r = 0; r < 4; ++r) s_acc[g][r] = 0.0f;

    const char* bp0 = blds + kg * 2048 + rl * 16;
    i32x8 bf0, bf1;

    #define PLOADB(FL)                                                            \
        {                                                                         \
            const char* bq = bp0 + ((FL) >> 2) * 16384 + ((FL) & 3) * 256;        \
            i32x4 l0 = *reinterpret_cast<const i32x4*>(bq);                       \
            i32x4 l1 = *reinterpret_cast<const i32x4*>(bq + 1024);                \
            i32x4 l2 = *reinterpret_cast<const i32x4*>(bq + 8192);                \
            i32x4 l3 = *reinterpret_cast<const i32x4*>(bq + 9216);                \
            bf0 = __builtin_shufflevector(l0, l1, 0, 1, 2, 3, 4, 5, 6, 7);        \
            bf1 = __builtin_shufflevector(l2, l3, 0, 1, 2, 3, 4, 5, 6, 7);        \
        }

    if constexpr (MODE == 2) {
        // ---- MFMA-only rate test: 8 independent self-accumulating MFMAs/phase.
        PSTAGE(0);
        __syncthreads();
        PLOADB(0);
        f32x4 acc[4], acc2[4];
        #pragma unroll
        for (int g = 0; g < 4; ++g) {
            acc[g]  = (f32x4){0.f, 0.f, 0.f, 0.f};
            acc2[g] = (f32x4){0.f, 0.f, 0.f, 0.f};
        }
        #pragma unroll 1
        for (int rep = 0; rep < 8; ++rep) {
            #pragma unroll 1
            for (int ph = 0; ph < 16; ++ph) {
                #pragma unroll
                for (int g = 0; g < 4; ++g)
                    asm("v_mfma_f32_16x16x128_f8f6f4 %0, %1, %2, %0"
                        : "+v"(acc[g]) : "v"(afrag[g][0]), "v"(bf0));
                #pragma unroll
                for (int g = 0; g < 4; ++g)
                    asm("v_mfma_f32_16x16x128_f8f6f4 %0, %1, %2, %0"
                        : "+v"(acc2[g]) : "v"(afrag[g][1]), "v"(bf1));
            }
        }
        asm volatile("s_nop 7");
        asm volatile("s_nop 7");
        asm volatile("s_nop 7");
        #pragma unroll
        for (int g = 0; g < 4; ++g)
            #pragma unroll
            for (int r = 0; r < 4; ++r) s_acc[g][r] = acc[g][r] + acc2[g][r];
    } else {
        // ---- full-structure modes (0 = r18 chained+pingpong; 1 = split-acc).
        f32x4 accA[4], accB[4], accA2[4], accB2[4];

        #define PMFMA8C(ACC)                                                      \
            {                                                                     \
                _Pragma("unroll")                                                 \
                for (int g = 0; g < 4; ++g) ACC[g] = (f32x4){0.f, 0.f, 0.f, 0.f}; \
                _Pragma("unroll")                                                 \
                for (int g = 0; g < 4; ++g)                                       \
                    asm("v_mfma_f32_16x16x128_f8f6f4 %0, %1, %2, %0"              \
                        : "+v"(ACC[g]) : "v"(afrag[g][0]), "v"(bf0));             \
                _Pragma("unroll")                                                 \
                for (int g = 0; g < 4; ++g)                                       \
                    asm("v_mfma_f32_16x16x128_f8f6f4 %0, %1, %2, %0"              \
                        : "+v"(ACC[g]) : "v"(afrag[g][1]), "v"(bf1));             \
            }

        #define PMFMA8S(ACC, ACC2)                                                \
            {                                                                     \
                _Pragma("unroll")                                                 \
                for (int g = 0; g < 4; ++g) {                                     \
                    ACC[g]  = (f32x4){0.f, 0.f, 0.f, 0.f};                        \
                    ACC2[g] = (f32x4){0.f, 0.f, 0.f, 0.f};                        \
                }                                                                 \
                _Pragma("unroll")                                                 \
                for (int g = 0; g < 4; ++g)                                       \
                    asm("v_mfma_f32_16x16x128_f8f6f4 %0, %1, %2, %0"              \
                        : "+v"(ACC[g]) : "v"(afrag[g][0]), "v"(bf0));             \
                _Pragma("unroll")                                                 \
                for (int g = 0; g < 4; ++g)                                       \
                    asm("v_mfma_f32_16x16x128_f8f6f4 %0, %1, %2, %0"              \
                        : "+v"(ACC2[g]) : "v"(afrag[g][1]), "v"(bf1));            \
            }

        #define PEXPSUM1(ACC, F)                                                  \
            {                                                                     \
                float cthr = 0.0f;                                                \
                _Pragma("unroll")                                                 \
                for (int g = 0; g < 4; ++g)                                       \
                    _Pragma("unroll")                                             \
                    for (int r = 0; r < 4; ++r) {                                 \
                        float e = __builtin_amdgcn_exp2f(                         \
                            fmaf(ACC[g][r], EXPC, EXPB));                         \
                        s_acc[g][r] += e;                                         \
                        cthr += e;                                                \
                    }                                                             \
                cthr += __shfl_xor(cthr, 16, 64);                                 \
                cthr += __shfl_xor(cthr, 32, 64);                                 \
                if (offdiag && lane < 16) cs[wave][(F) * 16 + rl] = cthr;         \
            }

        #define PEXPSUM2(ACC, ACC2, F)                                            \
            {                                                                     \
                float cthr = 0.0f;                                                \
                _Pragma("unroll")                                                 \
                for (int g = 0; g < 4; ++g)                                       \
                    _Pragma("unroll")                                             \
                    for (int r = 0; r < 4; ++r) {                                 \
                        float e = __builtin_amdgcn_exp2f(                         \
                            fmaf(ACC[g][r] + ACC2[g][r], EXPC, EXPB));            \
                        s_acc[g][r] += e;                                         \
                        cthr += e;                                                \
                    }                                                             \
                cthr += __shfl_xor(cthr, 16, 64);                                 \
                cthr += __shfl_xor(cthr, 32, 64);                                 \
                if (offdiag && lane < 16) cs[wave][(F) * 16 + rl] = cthr;         \
            }

        #pragma unroll 1
        for (int rep = 0; rep < 8; ++rep) {
            #pragma unroll 1
            for (int half = 0; half < 2; ++half) {
                PSTAGE(half);
                __syncthreads();
                if constexpr (MODE == 0) {
                    PLOADB(0); PMFMA8C(accA);
                    #pragma unroll 1
                    for (int fo = 0; fo < 3; ++fo) {
                        const int f1 = 2 * fo + 1, f2 = 2 * fo + 2;
                        PLOADB(f1); PMFMA8C(accB);
                        asm volatile("s_nop 7");
                        PEXPSUM1(accA, f1 - 1);
                        PLOADB(f2); PMFMA8C(accA);
                        asm volatile("s_nop 7");
                        PEXPSUM1(accB, f2 - 1);
                    }
                    PLOADB(7); PMFMA8C(accB);
                    asm volatile("s_nop 7");
                    PEXPSUM1(accA, 6);
                    asm volatile("s_nop 7");
                    PEXPSUM1(accB, 7);
                } else {
                    #pragma unroll 1
                    for (int fl = 0; fl < 8; ++fl) {
                        PLOADB(fl);
                        PMFMA8S(accA, accA2);
                        asm volatile("s_nop 7");
                        asm volatile("s_nop 7");
                        asm volatile("s_nop 7");
                        PEXPSUM2(accA, accA2, fl);
                    }
                }
                __syncthreads();
            }
        }
        #undef PMFMA8C
        #undef PMFMA8S
        #undef PEXPSUM1
        #undef PEXPSUM2
    }

    // sink (never read)
    #pragma unroll
    for (int g = 0; g < 4; ++g)
        #pragma unroll
        for (int r = 0; r < 4; ++r) {
            float v = s_acc[g][r];
            #pragma unroll
            for (int off = 1; off < 16; off <<= 1) v += __shfl_xor(v, off, 64);
            if (rl == 0)
                pout[chunk * N_SZ + i0 + g * 16 + kg * 4 + r] = v;
        }
    if (offdiag) {
        __syncthreads();
        float v = cs[0][t] + cs[1][t] + cs[2][t] + cs[3][t];
        pout[rt * N_SZ + chunk * 256 + t] = v;
    }
    #undef PSTAGE
    #undef PLOADB
}

// ---- Kernel 3: per-row lse - pos; device-scope atomic final reduce (r18) ----
__global__ __launch_bounds__(256) void rowsum_kernel(const float* __restrict__ partial,
                                                     const float* __restrict__ pos,
                                                     float* __restrict__ accf,
                                                     unsigned* __restrict__ counter,
                                                     float* __restrict__ out) {
    const int row = blockIdx.x * 256 + threadIdx.x;
    float s = -1.0f;
    #pragma unroll
    for (int c = 0; c < 32; ++c) s += partial[c * N_SZ + row];
    float acc = 2.0f + logf(s) - pos[row];
    #pragma unroll
    for (int off = 32; off; off >>= 1) acc += __shfl_xor(acc, off, 64);
    __shared__ float w[4];
    if ((threadIdx.x & 63) == 0) w[threadIdx.x >> 6] = acc;
    __syncthreads();
    if (threadIdx.x == 0) {
        atomicAdd(accf, w[0] + w[1] + w[2] + w[3]);
        __threadfence();
        unsigned old = atomicAdd(counter, 1u);
        if (old == 31u) {
            float tot = atomicAdd(accf, 0.0f);
            out[0] = tot / (float)N_SZ;
        }
    }
}

extern "C" void kernel_launch(void* const* d_in, const int* in_sizes, int n_in,
                              void* d_out, int out_size, void* d_ws, size_t ws_size,
                              hipStream_t stream) {
    const float* zi = (const float*)d_in[0];
    const float* zj = (const float*)d_in[1];

    char* ws = (char*)d_ws;
    char* znb       = ws;                                   // 2 MB fp8 k-seg layout
    float* pos      = (float*)(ws + 2097152);               // 32 KB
    float* partial  = (float*)(ws + 2097152 + 32768);       // 1 MB
    float* accf     = (float*)(ws + 2097152 + 32768 + 1048576);
    unsigned* counter = (unsigned*)(ws + 2097152 + 32768 + 1048576 + 4);
    float* probebuf = (float*)(ws + 2097152 + 32768 + 1048576 + 64);  // 1 MB scratch
    float* out = (float*)d_out;

    prep_kernel<<<B_SZ / 4, 256, 0, stream>>>(zi, zj, znb, pos, accf, counter);
    // --- DECISION PROBES (timing-only; results never read) ---
    probe_kernel<0><<<528, 256, 0, stream>>>(znb, probebuf);  // r18 anchor
    probe_kernel<1><<<528, 256, 0, stream>>>(znb, probebuf);  // split-acc ILP test
    probe_kernel<2><<<528, 256, 0, stream>>>(znb, probebuf);  // raw MFMA rate test
    // --- real computation (r18 frozen) ---
    simlse_kernel<<<528, 256, 0, stream>>>(znb, partial);
    rowsum_kernel<<<32, 256, 0, stream>>>(partial, pos, accf, counter, out);
}

// Round 25
// 31.820 us; speedup vs baseline: 9.6479x; 9.6479x over previous
//
#include <hip/hip_runtime.h>
#include <hip/hip_bf16.h>
#include <cmath>

#define B_SZ 4096
#define N_SZ 8192
#define D_SZ 256
#define EPS 1e-8f
// zn is stored as fp8 e4m3 scaled by 16 -> acc = 256*cos.
// exp(sim-2) with sim = 2*cos = acc/128:  exp2( acc*log2e/128 - 2*log2e )
#define EXPC 0.01127105500694503f      // log2(e)/128
#define EXPB -2.8853900817779268f      // -2*log2(e)
#define SCL1 0x7F                      // e8m0 unit scale: 2^(127-127) = 1.0

typedef __attribute__((ext_vector_type(4))) float f32x4;
typedef __attribute__((ext_vector_type(4))) int   i32x4;
typedef __attribute__((ext_vector_type(8))) int   i32x8;

__device__ __forceinline__ void dma16(const void* g, void* l) {
    __builtin_amdgcn_global_load_lds(
        (const __attribute__((address_space(1))) unsigned int*)g,
        (__attribute__((address_space(3))) unsigned int*)l, 16, 0, 0);
}

// fp8 k-segment-transposed panel layout (1 byte/elem):
//   byte(row,k) = (row>>6)*16384 + (k>>4)*1024 + (row&63)*16 + (k&15)
// subpanel = 64 rows x 256 k = 16 KB. One K=128 MFMA operand (32 fp8) = two
// 16-B loads 1024 B apart.

// ---- Kernel 1: norms + pos (fp32 exact) + fp8 ZN + zero the reduce ctrl. ----
__global__ __launch_bounds__(256) void prep_kernel(const float* __restrict__ zi,
                                                   const float* __restrict__ zj,
                                                   char* __restrict__ znb,
                                                   float* __restrict__ pos,
                                                   float* __restrict__ accf,
                                                   unsigned* __restrict__ counter) {
    if (blockIdx.x == 0 && threadIdx.x == 0) { *accf = 0.0f; *counter = 0u; }
    const int wave = threadIdx.x >> 6, lane = threadIdx.x & 63;
    const int i = blockIdx.x * 4 + wave;               // 0..B-1
    float4 a = reinterpret_cast<const float4*>(zi + (size_t)i * D_SZ)[lane];
    float4 b = reinterpret_cast<const float4*>(zj + (size_t)i * D_SZ)[lane];
    float ssa = a.x * a.x + a.y * a.y + a.z * a.z + a.w * a.w;
    float ssb = b.x * b.x + b.y * b.y + b.z * b.z + b.w * b.w;
    float dab = a.x * b.x + a.y * b.y + a.z * b.z + a.w * b.w;
    #pragma unroll
    for (int off = 32; off; off >>= 1) {
        ssa += __shfl_xor(ssa, off, 64);
        ssb += __shfl_xor(ssb, off, 64);
        dab += __shfl_xor(dab, off, 64);
    }
    const float invna = 1.0f / fmaxf(sqrtf(ssa), EPS);
    const float invnb = 1.0f / fmaxf(sqrtf(ssb), EPS);
    if (lane == 0) {
        float p = dab * invna * invnb * 2.0f;
        pos[i] = p;
        pos[i + B_SZ] = p;
    }
    // lane covers k = 4*lane .. 4*lane+3; seg = lane>>2, in-seg byte = (lane&3)*4.
    const float sa = invna * 16.0f, sb = invnb * 16.0f;
    const int koff = (lane >> 2) * 1024 + (lane & 3) * 4;
    {
        int pk = __builtin_amdgcn_cvt_pk_fp8_f32(a.x * sa, a.y * sa, 0, false);
        pk     = __builtin_amdgcn_cvt_pk_fp8_f32(a.z * sa, a.w * sa, pk, true);
        *reinterpret_cast<int*>(znb + (size_t)(i >> 6) * 16384 + koff + (i & 63) * 16) = pk;
    }
    {
        const int r = i + B_SZ;
        int pk = __builtin_amdgcn_cvt_pk_fp8_f32(b.x * sb, b.y * sb, 0, false);
        pk     = __builtin_amdgcn_cvt_pk_fp8_f32(b.z * sb, b.w * sb, pk, true);
        *reinterpret_cast<int*>(znb + (size_t)(r >> 6) * 16384 + koff + (r & 63) * 16) = pk;
    }
}

// ---- Kernel 2: r18 structure, MFMA via the SCALE builtin (unit scales) ----
// r24 probe finding: raw asm v_mfma_f32_16x16x128_f8f6f4 issues at ~169 cyc
// (~380 TF) even with 8 fully independent chains -> the raw opcode is the
// wall. The MX-rate path (4661 TF ubench, m21/m148) is the _scale_ builtin.
// Swap: __builtin_amdgcn_mfma_scale_f32_16x16x128_f8f6f4 with e8m0 scale
// 0x7F (=1.0) -> bit-identical math, compiler-owned hazards/scheduling.
__global__ __launch_bounds__(256, 3) void simlse_kernel(const char* __restrict__ znb,
                                                        float* __restrict__ partial) {
    __shared__ __attribute__((aligned(16))) char blds[32768];
    __shared__ float cs[4][256];

    const int t = threadIdx.x;
    const int wave = t >> 6, lane = t & 63;

    // XCD-paired decode: XCD x owns chunk-pairs (x, 31-x) and (x+8, 23-x).
    int rt, chunk;
    {
        const int x = blockIdx.x & 7;
        int j = blockIdx.x >> 3;                 // 0..65 within XCD
        int p = x;
        if (j >= 33) { j -= 33; p = x + 8; }
        if (j <= p) { rt = j; chunk = p; }
        else        { rt = j - (p + 1); chunk = 31 - p; }
    }
    const bool offdiag = (rt != chunk);

    const int rl = lane & 15;                    // A-row / B-col within fragment
    const int kg = lane >> 4;                    // 32-elem k-block index
    const int i0 = rt * 256 + wave * 64;         // wave's first row

    // Stage half H of chunk's panel (32 KB contiguous): 256 thr x 8 x 16 B.
    #define STAGE(H)                                                              \
        {                                                                         \
            const char* gp = znb + (size_t)chunk * 65536 + (H) * 32768 + t * 16;  \
            char* lp = blds + t * 16;                                             \
            _Pragma("unroll")                                                     \
            for (int c = 0; c < 8; ++c) dma16(gp + c * 4096, lp + c * 4096);      \
        }

    STAGE(0);                                    // issue half-0 DMA first

    // A panel: wave owns subpanel rt*4+wave (64 rows). 4 rowgroups x 2 k-chunks.
    const char* ap = znb + (size_t)(rt * 4 + wave) * 16384 + rl * 16;
    i32x8 afrag[4][2];
    #pragma unroll
    for (int g = 0; g < 4; ++g)
        #pragma unroll
        for (int kc = 0; kc < 2; ++kc) {
            i32x4 lo = *reinterpret_cast<const i32x4*>(
                ap + (kc * 8 + kg * 2) * 1024 + g * 256);
            i32x4 hi = *reinterpret_cast<const i32x4*>(
                ap + (kc * 8 + kg * 2 + 1) * 1024 + g * 256);
            afrag[g][kc] = __builtin_shufflevector(lo, hi, 0, 1, 2, 3, 4, 5, 6, 7);
        }

    float s_acc[4][4];
    #pragma unroll
    for (int g = 0; g < 4; ++g)
        #pragma unroll
        for (int r = 0; r < 4; ++r) s_acc[g][r] = 0.0f;

    // B base in LDS; local phase fl (0..7): addr = bp0 + (fl>>2)*16384 + (fl&3)*256
    //   (+8192 for kc=1, +1024 for hi 16 B of the 32-elem k-block)
    const char* bp0 = blds + kg * 2048 + rl * 16;

    i32x8 bf0, bf1;
    f32x4 accA[4], accB[4];

    #define LOADB(FL)                                                             \
        {                                                                         \
            const char* bq = bp0 + ((FL) >> 2) * 16384 + ((FL) & 3) * 256;        \
            i32x4 l0 = *reinterpret_cast<const i32x4*>(bq);                       \
            i32x4 l1 = *reinterpret_cast<const i32x4*>(bq + 1024);                \
            i32x4 l2 = *reinterpret_cast<const i32x4*>(bq + 8192);                \
            i32x4 l3 = *reinterpret_cast<const i32x4*>(bq + 9216);                \
            bf0 = __builtin_shufflevector(l0, l1, 0, 1, 2, 3, 4, 5, 6, 7);        \
            bf1 = __builtin_shufflevector(l2, l3, 0, 1, 2, 3, 4, 5, 6, 7);        \
        }

    // cbsz=0, blgp=0 (fp8 e4m3 x fp8 e4m3); op_sel 0; scale byte 0x7F = 1.0.
    #define MFMA8(ACC)                                                            \
        {                                                                         \
            _Pragma("unroll")                                                     \
            for (int g = 0; g < 4; ++g) {                                         \
                ACC[g] = (f32x4){0.f, 0.f, 0.f, 0.f};                             \
                ACC[g] = __builtin_amdgcn_mfma_scale_f32_16x16x128_f8f6f4(        \
                    afrag[g][0], bf0, ACC[g], 0, 0, 0, SCL1, 0, SCL1);            \
                ACC[g] = __builtin_amdgcn_mfma_scale_f32_16x16x128_f8f6f4(        \
                    afrag[g][1], bf1, ACC[g], 0, 0, 0, SCL1, 0, SCL1);            \
            }                                                                     \
        }

    #define EXPSUM(ACC, F)                                                        \
        {                                                                         \
            float cthr = 0.0f;                                                    \
            _Pragma("unroll")                                                     \
            for (int g = 0; g < 4; ++g)                                           \
                _Pragma("unroll")                                                 \
                for (int r = 0; r < 4; ++r) {                                     \
                    float e = __builtin_amdgcn_exp2f(fmaf(ACC[g][r], EXPC, EXPB)); \
                    s_acc[g][r] += e;                                             \
                    cthr += e;                                                    \
                }                                                                 \
            cthr += __shfl_xor(cthr, 16, 64);                                     \
            cthr += __shfl_xor(cthr, 32, 64);                                     \
            if (offdiag && lane < 16)                                             \
                cs[wave][(F) * 16 + rl] = cthr;                                   \
        }

    __syncthreads();                       // half-0 landed (drains vmcnt)

    // ---- half 0: global phases 0..7, acc ping-pong ----
    LOADB(0); MFMA8(accA);
    #pragma unroll 1
    for (int fo = 0; fo < 3; ++fo) {
        const int f1 = 2 * fo + 1, f2 = 2 * fo + 2;
        LOADB(f1); MFMA8(accB);
        EXPSUM(accA, f1 - 1);
        LOADB(f2); MFMA8(accA);
        EXPSUM(accB, f2 - 1);
    }
    LOADB(7); MFMA8(accB);
    EXPSUM(accA, 6);

    __syncthreads();                       // all waves done reading half 0
    STAGE(1);                              // issue half-1 DMA
    EXPSUM(accB, 7);                       // deferred exp hides under the DMA
    __syncthreads();                       // half-1 landed (drains vmcnt)

    // ---- half 1: global phases 8..15 ----
    LOADB(0); MFMA8(accA);
    #pragma unroll 1
    for (int fo = 0; fo < 3; ++fo) {
        const int f1 = 2 * fo + 1, f2 = 2 * fo + 2;
        LOADB(f1); MFMA8(accB);
        EXPSUM(accA, 8 + f1 - 1);
        LOADB(f2); MFMA8(accA);
        EXPSUM(accB, 8 + f2 - 1);
    }
    LOADB(7); MFMA8(accB);
    EXPSUM(accA, 14);
    EXPSUM(accB, 15);

    // Row-sums over the 16 col-lanes (rl); rows i0 + g*16 + kg*4 + r -> slot chunk.
    #pragma unroll
    for (int g = 0; g < 4; ++g)
        #pragma unroll
        for (int r = 0; r < 4; ++r) {
            float v = s_acc[g][r];
            #pragma unroll
            for (int off = 1; off < 16; off <<= 1) v += __shfl_xor(v, off, 64);
            if (rl == 0)
                partial[chunk * N_SZ + i0 + g * 16 + kg * 4 + r] = v;
        }

    // Col-sums: combine 4 waves, write 256 cols of the chunk-tile -> slot rt.
    if (offdiag) {
        __syncthreads();
        float v = cs[0][t] + cs[1][t] + cs[2][t] + cs[3][t];
        partial[rt * N_SZ + chunk * 256 + t] = v;
    }
    #undef STAGE
    #undef LOADB
    #undef MFMA8
    #undef EXPSUM
}

// ---- Kernel 3: per-row lse - pos; device-scope atomic final reduce ----
__global__ __launch_bounds__(256) void rowsum_kernel(const float* __restrict__ partial,
                                                     const float* __restrict__ pos,
                                                     float* __restrict__ accf,
                                                     unsigned* __restrict__ counter,
                                                     float* __restrict__ out) {
    const int row = blockIdx.x * 256 + threadIdx.x;
    float s = -1.0f;                       // remove diagonal exp(~0)=1
    #pragma unroll
    for (int c = 0; c < 32; ++c) s += partial[c * N_SZ + row];
    float acc = 2.0f + logf(s) - pos[row];
    #pragma unroll
    for (int off = 32; off; off >>= 1) acc += __shfl_xor(acc, off, 64);
    __shared__ float w[4];
    if ((threadIdx.x & 63) == 0) w[threadIdx.x >> 6] = acc;
    __syncthreads();
    if (threadIdx.x == 0) {
        atomicAdd(accf, w[0] + w[1] + w[2] + w[3]);
        __threadfence();
        unsigned old = atomicAdd(counter, 1u);
        if (old == 31u) {
            float tot = atomicAdd(accf, 0.0f);     // atomic read of final sum
            out[0] = tot / (float)N_SZ;
        }
    }
}

extern "C" void kernel_launch(void* const* d_in, const int* in_sizes, int n_in,
                              void* d_out, int out_size, void* d_ws, size_t ws_size,
                              hipStream_t stream) {
    const float* zi = (const float*)d_in[0];
    const float* zj = (const float*)d_in[1];

    char* ws = (char*)d_ws;
    char* znb       = ws;                                   // 2 MB fp8 k-seg layout
    float* pos      = (float*)(ws + 2097152);               // 32 KB
    float* partial  = (float*)(ws + 2097152 + 32768);       // 32*8192*4 = 1 MB
    float* accf     = (float*)(ws + 2097152 + 32768 + 1048576);
    unsigned* counter = (unsigned*)(ws + 2097152 + 32768 + 1048576 + 4);
    float* out = (float*)d_out;

    prep_kernel<<<B_SZ / 4, 256, 0, stream>>>(zi, zj, znb, pos, accf, counter);
    simlse_kernel<<<528, 256, 0, stream>>>(znb, partial);
    rowsum_kernel<<<32, 256, 0, stream>>>(partial, pos, accf, counter, out);
}